// Round 4
// baseline (93.235 us; speedup 1.0000x reference)
//
#include <hip/hip_runtime.h>

constexpr int FIELD = 26;
constexpr int EDIM  = 32;
constexpr int NPAIR = 325;   // C(26,2)
constexpr int TP    = 5;     // pairs per block (5 divides 325)
constexpr int BT    = 64;    // batch rows per block (16 per wave)
constexpr int CHUNK = TP * EDIM * 4;          // 640 B of out per row per block

typedef __bf16 bf16x8 __attribute__((ext_vector_type(8)));
typedef float  f32x4  __attribute__((ext_vector_type(4)));

static __device__ inline bf16x8 cvt8(const float4 a, const float4 b) {
    bf16x8 r;
    r[0] = (__bf16)a.x; r[1] = (__bf16)a.y; r[2] = (__bf16)a.z; r[3] = (__bf16)a.w;
    r[4] = (__bf16)b.x; r[5] = (__bf16)b.y; r[6] = (__bf16)b.z; r[7] = (__bf16)b.w;
    return r;
}

__global__ __launch_bounds__(256) void bilinear_mfma_staged(
    const float* __restrict__ x,     // [B][26][32]
    const float* __restrict__ W,     // [325][32][32]  W[p][e][d]
    const float* __restrict__ bias,  // [325][32]
    float* __restrict__ out)         // [B][325][32]
{
    const int pc = blockIdx.x;       // pair-chunk 0..64  (fastest -> blocks share batch tile)
    const int p0 = pc * TP;
    const int b0 = blockIdx.y * BT;

    // result tile [TP][BT][EDIM] f32, float4-column XOR-swizzled by row
    __shared__ float tile[TP * BT * EDIM];   // 40 KB

    const int tid  = threadIdx.x;
    const int wv   = tid >> 6;       // wave 0..3
    const int l    = tid & 63;
    const int lr   = l & 15;         // MFMA col index (batch) within 16-tile
    const int g    = l >> 4;         // k-group 0..3
    const int bloc = wv * 16 + lr;   // block-local batch row 0..63
    const int b    = b0 + bloc;

    // triu_indices(26,1) decode for p0, then walk the next TP-1 pairs.
    int fi[TP], fj[TP];
    {
        int f = 0, rem = p0;
        #pragma unroll 1
        while (rem >= FIELD - 1 - f) { rem -= FIELD - 1 - f; ++f; }
        int jj = f + 1 + rem;
        #pragma unroll
        for (int q = 0; q < TP; ++q) {
            fi[q] = f; fj[q] = jj;
            if (++jj == FIELD) { ++f; jj = f + 1; }
        }
    }

    // ---- Compute: per pair, global->reg fragments, bf16 MFMA, epilogue, stage to LDS.
    #pragma unroll
    for (int q = 0; q < TP; ++q) {
        const float* xp = x + ((size_t)b * FIELD + fi[q]) * EDIM + g * 8;
        const bf16x8 xf = cvt8(*(const float4*)xp, *(const float4*)(xp + 4));

        #pragma unroll
        for (int n = 0; n < 2; ++n) {
            const float* wp = W + ((size_t)(p0 + q) * EDIM + n * 16 + lr) * EDIM + g * 8;
            const bf16x8 wf = cvt8(*(const float4*)wp, *(const float4*)(wp + 4));

            const f32x4 acc = __builtin_amdgcn_mfma_f32_16x16x32_bf16(
                wf, xf, (f32x4){0.f, 0.f, 0.f, 0.f}, 0, 0, 0);

            // lane holds D[e][b]: e = n*16 + g*4 + reg, b = this lane's `b`
            const int e0 = n * 16 + g * 4;
            const float4 b4  = *(const float4*)(bias + (size_t)(p0 + q) * EDIM + e0);
            const float4 xj4 = *(const float4*)(x + ((size_t)b * FIELD + fj[q]) * EDIM + e0);
            float4 r;
            r.x = (acc[0] + b4.x) * xj4.x;
            r.y = (acc[1] + b4.y) * xj4.y;
            r.z = (acc[2] + b4.z) * xj4.z;
            r.w = (acc[3] + b4.w) * xj4.w;

            const int c = (e0 >> 2) ^ (bloc & 7);   // swizzled float4 column
            *(float4*)(&tile[(q * BT + bloc) * EDIM + (c << 2)]) = r;
        }
    }

    __syncthreads();

    // ---- Store: flat sweep, consecutive lanes -> consecutive global bytes.
    // out chunk per row = TP*EDIM*4 = 640 B contiguous.
    #pragma unroll
    for (int it = 0; it < (TP * BT * EDIM * 4) / (256 * 16); ++it) {   // 10
        const int o   = (it * 256 + tid) * 16;     // byte offset in block's out chunk
        const int bb  = o / CHUNK;                 // block-local row
        const int rem = o - bb * CHUNK;
        const int pp  = rem >> 7;                  // pair within chunk
        const int cc  = (rem >> 4) & 7;            // float4 column
        const float4 v = *(const float4*)(&tile[(pp * BT + bb) * EDIM + ((cc ^ (bb & 7)) << 2)]);
        *(float4*)(out + ((size_t)(b0 + bb) * NPAIR + p0 + pp) * EDIM + (cc << 2)) = v;
    }
}

extern "C" void kernel_launch(void* const* d_in, const int* in_sizes, int n_in,
                              void* d_out, int out_size, void* d_ws, size_t ws_size,
                              hipStream_t stream) {
    const float* x    = (const float*)d_in[0];
    const float* W    = (const float*)d_in[1];
    const float* bias = (const float*)d_in[2];
    float* out        = (float*)d_out;

    const int B = in_sizes[0] / (FIELD * EDIM);   // 4096
    dim3 grid(NPAIR / TP, B / BT);                // p-chunk fastest: dense concurrent out coverage
    bilinear_mfma_staged<<<grid, dim3(256), 0, stream>>>(x, W, bias, out);
}